// Round 1
// 181.625 us; speedup vs baseline: 1.0085x; 1.0085x over previous
//
#include <hip/hip_runtime.h>
#include <hip/hip_bf16.h>
#include <stdint.h>
#include <stddef.h>

typedef __bf16 bf16_t;
typedef __bf16 bf16x4 __attribute__((ext_vector_type(4)));
typedef __bf16 bf16x8 __attribute__((ext_vector_type(8)));
typedef float f32x4 __attribute__((ext_vector_type(4)));
typedef float f32x16 __attribute__((ext_vector_type(16)));

#define MFMA16(a, b, c) __builtin_amdgcn_mfma_f32_16x16x32_bf16(a, b, c, 0, 0, 0)
#define MFMA32(a, b, c) __builtin_amdgcn_mfma_f32_32x32x16_bf16(a, b, c, 0, 0, 0)

// async global->LDS, 16 B per lane; LDS dest = uniform base + lane*16
#define GLL16(g, l)                                                      \
    __builtin_amdgcn_global_load_lds(                                    \
        (const __attribute__((address_space(1))) void*)(g),              \
        (__attribute__((address_space(3))) void*)(l), 16, 0, 0)

#define SEQ 2048
#define NHEAD 16
#define HD 64
#define HID 1024
#define QKV_LD 3072
#define VT_LD 2080  // 2048 + 32 pad: breaks 4 KB power-of-2 L2 set aliasing

// ---------------------------------------------------------------------------
// Fused prep: cast x -> bf16 (blocks 0..4095), transpose+cast w_qkv
// (4096..7167), transpose+cast w_out (7168..8191).
// ---------------------------------------------------------------------------
__global__ __launch_bounds__(256)
void prep_kernel(const float* __restrict__ x, const float* __restrict__ w_qkv,
                 const float* __restrict__ w_out, bf16_t* __restrict__ xbf,
                 bf16_t* __restrict__ wqkvT, bf16_t* __restrict__ woutT) {
    int L = blockIdx.x;
    int tid = threadIdx.x;
    if (L < 4096) {  // cast x
        int i = (L * 256 + tid) * 4;
        float4 v = *(const float4*)(x + i);
        bf16x4 o = {(bf16_t)v.x, (bf16_t)v.y, (bf16_t)v.z, (bf16_t)v.w};
        *(bf16x4*)(xbf + i) = o;
        return;
    }
    __shared__ bf16_t tile[32][33];
    const float* W;
    bf16_t* Wt;
    int N, bx, by;
    if (L < 7168) {
        int r = L - 4096;
        W = w_qkv; Wt = wqkvT; N = 3072; bx = r % 96; by = r / 96;
    } else {
        int r = L - 7168;
        W = w_out; Wt = woutT; N = 1024; bx = r % 32; by = r / 32;
    }
    int K = 1024;
    int n0 = bx * 32, k0 = by * 32;
    int tx = tid & 31, ty = tid >> 5;  // 32 x 8
#pragma unroll
    for (int i = 0; i < 4; i++)
        tile[ty + i * 8][tx] = (bf16_t)W[(size_t)(k0 + ty + i * 8) * N + n0 + tx];
    __syncthreads();
#pragma unroll
    for (int i = 0; i < 4; i++)
        Wt[(size_t)(n0 + ty + i * 8) * K + k0 + tx] = tile[tx][ty + i * 8];
}

// ---------------------------------------------------------------------------
// V transpose prepass: Vt[bh][d][s] = qkv[b][s][2048 + h*64 + d].
// ---------------------------------------------------------------------------
__global__ __launch_bounds__(256)
void vt_transpose(const bf16_t* __restrict__ qkv, bf16_t* __restrict__ Vt) {
    int s0 = blockIdx.x * 64;
    int bh = blockIdx.y;
    int b = bh >> 4, h = bh & 15;
    int tid = threadIdx.x;
    __shared__ __align__(16) bf16_t tile[64][72];

    int row = tid >> 3, c8 = (tid & 7) * 8;
#pragma unroll
    for (int it = 0; it < 2; it++) {
        int sr = row + it * 32;
        bf16x8 v = *(const bf16x8*)(qkv + ((size_t)b * SEQ + s0 + sr) * QKV_LD +
                                    2 * HID + h * HD + c8);
        *(bf16x8*)(&tile[sr][c8]) = v;
    }
    __syncthreads();
#pragma unroll
    for (int it = 0; it < 2; it++) {
        int d = row + it * 32;
        bf16x8 w;
#pragma unroll
        for (int e = 0; e < 8; e++) w[e] = tile[c8 + e][d];
        *(bf16x8*)(Vt + ((size_t)bh * HD + d) * VT_LD + s0 + c8) = w;
    }
}

// ---------------------------------------------------------------------------
// QKV GEMM, 256x256 tile, BK=64, 8-phase schedule (T1+T2+T3+T4+T5).
// C[M][N] = A[M][K] @ Bt[N][K]^T + bias[N], bf16 out.
//
// 512 thr = 8 waves (2M x 4N); per-wave output 128x64; 16 MFMA_16x16x32 per
// phase (one 64x32 quadrant x K=64).  LDS 128 KiB: [2 dbuf][256][64] A and B.
//
// LDS chunk swizzle (T2): row of 64 bf16 = 8 chunks of 16 B; stored chunk
// c holds global chunk c ^ (row&7).  GLL16 dest stays linear (HW requires
// uniform base + lane*16); the *global* source chunk is pre-swizzled; the
// same XOR is applied on ds_read_b128.  -> 8 dwords/bank (minimum) per read.
//
// Staging order (2 GLL16 = one half-tile per phase), derived from region
// retirement (all waves' last read of a region precedes the staging phase
// by at least one barrier):
//   B-half0 last read ph2, A-half0 ph3, B-half1 ph2, A-half1 ph3.
//   compute tile t:  ph1 stage (t+1) B-half1 -> other buf (free)
//                    ph2 stage (t+1) A-half1 -> other buf (free)
//                    ph3 stage (t+2) B-half0 -> current buf (retired ph2)
//                    ph4 stage (t+2) A-half0 -> current buf (retired ph3)
// Counted drain: single s_waitcnt vmcnt(4) per K-tile at ph4 (drains the 8
// loads of tile t+1, leaves t+2's first 4 in flight).  Never vmcnt(0) in
// steady state.  Raw s_barrier (no full waitcnt drain) x2 per phase.
// ---------------------------------------------------------------------------
#define STAGE8(GB, LB, KOFF)                                                   \
    do {                                                                       \
        GLL16((GB) + (size_t)srow * K + (KOFF) + ssw,                          \
              (LB) + srow * 64 + (scl << 3));                                  \
        GLL16((GB) + (size_t)(srow + 64) * K + (KOFF) + ssw,                   \
              (LB) + (srow + 64) * 64 + (scl << 3));                           \
    } while (0)

__global__ __launch_bounds__(512, 2)
void gemm_qkv_8ph(const bf16_t* __restrict__ A, const bf16_t* __restrict__ Bt,
                  const float* __restrict__ bias, bf16_t* __restrict__ C,
                  int M, int N, int K) {
    __shared__ __align__(16) bf16_t As[2][256][64];
    __shared__ __align__(16) bf16_t Bs[2][256][64];

    // T1: bijective XCD swizzle (gridDim.x % 8 == 0)
    int nbx = N >> 8;
    int bid = blockIdx.x;
    int swz = (bid & 7) * (gridDim.x >> 3) + (bid >> 3);
    int m0 = (swz / nbx) << 8;
    int n0 = (swz % nbx) << 8;

    int tid = threadIdx.x;
    int lane = tid & 63;
    int wave = tid >> 6;
    int l16 = lane & 15, quad = lane >> 4;
    int wm = (wave >> 2) << 7;  // 0 / 128
    int wn = (wave & 3) << 6;   // 0 / 64 / 128 / 192

    // staging coords: 512 thr x 16 B = one 64-row sweep; 8 chunks/row
    int srow = tid >> 3;  // 0..63
    int scl = tid & 7;
    int ssw = ((scl ^ (srow & 7)) << 3);  // pre-swizzled global chunk offset

    const bf16_t* Ab = A + (size_t)m0 * K;
    const bf16_t* Bb = Bt + (size_t)n0 * K;

    f32x4 acc[8][4] = {};  // [msub*4+mt][nsub*2+nt]
    bf16x8 af[4][2], b0[2][2], b1[2][2];

    const int NT = K >> 6;  // 16 K-tiles of 64

    // ---- prologue: tile0 H1..H4, tile1 H1,H2; drain tile0 (vmcnt(4)) ----
    STAGE8(Bb, &Bs[0][0][0], 0);                        // t0 B-half0
    STAGE8(Ab, &As[0][0][0], 0);                        // t0 A-half0
    STAGE8(Bb + (size_t)128 * K, &Bs[0][128][0], 0);    // t0 B-half1
    STAGE8(Ab + (size_t)128 * K, &As[0][128][0], 0);    // t0 A-half1
    STAGE8(Bb, &Bs[1][0][0], 64);                       // t1 B-half0
    STAGE8(Ab, &As[1][0][0], 64);                       // t1 A-half0
    asm volatile("s_waitcnt vmcnt(4)" ::: "memory");
    __builtin_amdgcn_s_barrier();

    for (int t = 0; t < NT; t++) {
        int buf = t & 1;
        const bf16_t* Asb = &As[buf][0][0];
        const bf16_t* Bsb = &Bs[buf][0][0];
        int k1 = (t + 1) << 6;
        int k2 = (t + 2) << 6;

        // ===== phase 1: read A-msub0 + B-nsub0; stage (t+1) B-half1 =====
#pragma unroll
        for (int mt = 0; mt < 4; mt++) {
            int row = wm + mt * 16 + l16;
#pragma unroll
            for (int ks = 0; ks < 2; ks++)
                af[mt][ks] = *(const bf16x8*)(
                    Asb + row * 64 + (((ks * 4 + quad) ^ (row & 7)) << 3));
        }
#pragma unroll
        for (int nt = 0; nt < 2; nt++) {
            int row = wn + nt * 16 + l16;
#pragma unroll
            for (int ks = 0; ks < 2; ks++)
                b0[nt][ks] = *(const bf16x8*)(
                    Bsb + row * 64 + (((ks * 4 + quad) ^ (row & 7)) << 3));
        }
        if (t + 1 < NT) STAGE8(Bb + (size_t)128 * K, &Bs[buf ^ 1][128][0], k1);
        __builtin_amdgcn_s_barrier();
        asm volatile("s_waitcnt lgkmcnt(0)" ::: "memory");
        __builtin_amdgcn_s_setprio(1);
#pragma unroll
        for (int mt = 0; mt < 4; mt++)
#pragma unroll
            for (int nt = 0; nt < 2; nt++)
#pragma unroll
                for (int ks = 0; ks < 2; ks++)
                    acc[mt][nt] = MFMA16(af[mt][ks], b0[nt][ks], acc[mt][nt]);
        __builtin_amdgcn_s_setprio(0);
        __builtin_amdgcn_s_barrier();

        // ===== phase 2: read B-nsub1; stage (t+1) A-half1 =====
#pragma unroll
        for (int nt = 0; nt < 2; nt++) {
            int row = wn + 32 + nt * 16 + l16;
#pragma unroll
            for (int ks = 0; ks < 2; ks++)
                b1[nt][ks] = *(const bf16x8*)(
                    Bsb + row * 64 + (((ks * 4 + quad) ^ (row & 7)) << 3));
        }
        if (t + 1 < NT) STAGE8(Ab + (size_t)128 * K, &As[buf ^ 1][128][0], k1);
        __builtin_amdgcn_s_barrier();
        asm volatile("s_waitcnt lgkmcnt(0)" ::: "memory");
        __builtin_amdgcn_s_setprio(1);
#pragma unroll
        for (int mt = 0; mt < 4; mt++)
#pragma unroll
            for (int nt = 0; nt < 2; nt++)
#pragma unroll
                for (int ks = 0; ks < 2; ks++)
                    acc[mt][2 + nt] =
                        MFMA16(af[mt][ks], b1[nt][ks], acc[mt][2 + nt]);
        __builtin_amdgcn_s_setprio(0);
        __builtin_amdgcn_s_barrier();

        // ===== phase 3: read A-msub1; stage (t+2) B-half0 (current buf) =====
#pragma unroll
        for (int mt = 0; mt < 4; mt++) {
            int row = wm + 64 + mt * 16 + l16;
#pragma unroll
            for (int ks = 0; ks < 2; ks++)
                af[mt][ks] = *(const bf16x8*)(
                    Asb + row * 64 + (((ks * 4 + quad) ^ (row & 7)) << 3));
        }
        if (t + 2 < NT) STAGE8(Bb, &Bs[buf][0][0], k2);
        __builtin_amdgcn_s_barrier();
        asm volatile("s_waitcnt lgkmcnt(0)" ::: "memory");
        __builtin_amdgcn_s_setprio(1);
#pragma unroll
        for (int mt = 0; mt < 4; mt++)
#pragma unroll
            for (int nt = 0; nt < 2; nt++)
#pragma unroll
                for (int ks = 0; ks < 2; ks++)
                    acc[4 + mt][nt] =
                        MFMA16(af[mt][ks], b0[nt][ks], acc[4 + mt][nt]);
        __builtin_amdgcn_s_setprio(0);
        __builtin_amdgcn_s_barrier();

        // ===== phase 4: stage (t+2) A-half0 (current buf); counted drain ====
        if (t + 2 < NT) {
            STAGE8(Ab, &As[buf][0][0], k2);
            asm volatile("s_waitcnt vmcnt(4)" ::: "memory");
        } else if (t + 1 < NT) {
            asm volatile("s_waitcnt vmcnt(0)" ::: "memory");
        }
        __builtin_amdgcn_s_barrier();
        __builtin_amdgcn_s_setprio(1);
#pragma unroll
        for (int mt = 0; mt < 4; mt++)
#pragma unroll
            for (int nt = 0; nt < 2; nt++)
#pragma unroll
                for (int ks = 0; ks < 2; ks++)
                    acc[4 + mt][2 + nt] =
                        MFMA16(af[mt][ks], b1[nt][ks], acc[4 + mt][2 + nt]);
        __builtin_amdgcn_s_setprio(0);
        __builtin_amdgcn_s_barrier();
    }

    // ---- epilogue: bias + bf16 store.  C/D: col=l16, row=quad*4+reg ----
#pragma unroll
    for (int mi = 0; mi < 8; mi++) {
        int row = m0 + wm + (mi >> 2) * 64 + (mi & 3) * 16 + quad * 4;
#pragma unroll
        for (int ni = 0; ni < 4; ni++) {
            int col = n0 + wn + (ni >> 1) * 32 + (ni & 1) * 16 + l16;
            float bv = bias[col];
#pragma unroll
            for (int r = 0; r < 4; r++)
                C[(size_t)(row + r) * N + col] = (bf16_t)(acc[mi][ni][r] + bv);
        }
    }
}

// ---------------------------------------------------------------------------
// GEMM: C[M][N] = A[M][K] @ Bt[N][K]^T + bias[N].  bf16, fp32 accum, OutT out.
// 128xTN tile, BK=32, 256 thr, GLL width-16 staging into unpadded LDS.
// (kept for the out-projection: N=1024 -> 256^2 tiles would give only 64 wgs)
// ---------------------------------------------------------------------------
template <typename OutT, int TN>
__global__ __launch_bounds__(256)
void gemm_bt_bias(const bf16_t* __restrict__ A, const bf16_t* __restrict__ Bt,
                  const float* __restrict__ bias, OutT* __restrict__ C,
                  int M, int N, int K) {
    constexpr int NT = TN / 32;  // acc n-tiles per wave
    __shared__ __align__(16) bf16_t As[128][32];
    __shared__ __align__(16) bf16_t Bs[TN][32];

    int m0 = blockIdx.y * 128;
    int n0 = blockIdx.x * TN;
    int tid = threadIdx.x;
    int wave = tid >> 6, lane = tid & 63;
    int quad = lane >> 4, l16 = lane & 15;
    int wm = (wave >> 1) * 64, wn = (wave & 1) * (TN / 2);

    f32x4 acc[4][NT] = {};

    const bf16_t* a_base =
        A + (size_t)(m0 + wave * 32 + (lane >> 2)) * K + (lane & 3) * 8;
    const bf16_t* b_base =
        Bt + (size_t)(n0 + wave * (TN / 4) + (lane >> 2)) * K + (lane & 3) * 8;
    bf16_t* as_base = &As[wave * 32][0];
    bf16_t* bs_base = &Bs[wave * (TN / 4)][0];

    for (int k0 = 0; k0 < K; k0 += 32) {
        GLL16(a_base + k0, as_base);
        GLL16(a_base + 16 * K + k0, as_base + 16 * 32);
        GLL16(b_base + k0, bs_base);
        if (TN == 128) GLL16(b_base + 16 * K + k0, bs_base + 16 * 32);
        __syncthreads();

        bf16x8 af[4], bfr[NT];
#pragma unroll
        for (int t = 0; t < 4; t++)
            af[t] = *(const bf16x8*)(&As[wm + t * 16 + l16][quad * 8]);
#pragma unroll
        for (int t = 0; t < NT; t++)
            bfr[t] = *(const bf16x8*)(&Bs[wn + t * 16 + l16][quad * 8]);
#pragma unroll
        for (int mt = 0; mt < 4; mt++)
#pragma unroll
            for (int nt = 0; nt < NT; nt++)
                acc[mt][nt] = MFMA16(af[mt], bfr[nt], acc[mt][nt]);
        __syncthreads();
    }

#pragma unroll
    for (int mt = 0; mt < 4; mt++) {
        int row = m0 + wm + mt * 16 + quad * 4;
#pragma unroll
        for (int nt = 0; nt < NT; nt++) {
            int col = n0 + wn + nt * 16 + l16;
            float bv = bias[col];
#pragma unroll
            for (int r = 0; r < 4; r++)
                C[(size_t)(row + r) * N + col] = (OutT)(acc[mt][nt][r] + bv);
        }
    }
}

// ---------------------------------------------------------------------------
// Attention, mask j >= i, built on mfma_f32_32x32x16_bf16 (half the LDS
// reads per FLOP vs 16x16x32 — the LDS issue pipe was ~90% saturated).
// TI=64, BJ=64, 4 waves; wave (ih=w&1, jh=w>>1):
//   QK: S^T quarter = K[j-half] . Q[i-half]^T  (A=K from LDS, B=Q in regs,
//       4 chained k-steps).  C-layout: i = lane&31 (fixed), j = r+8rq+4hi ->
//       Ps written as packed b64, row sums as per-lane scalar adds.
//   PV: O quarter (i-half ih, d-half jh) over all 64 j: A=Ps, B=Vs frags.
// 3 barriers/iter; Ps block-shared.  LDS 27.4 KB -> 5 blocks/CU capacity;
// grid 1024 (x=bh XCD-pin, y=tile LPT long-first) -> real oversubscription.
// Fragment mapping used: A/B[m|n = lane&31][k = (lane>>5)*8 + e];
// C/D: col = lane&31, row = (reg&3) + 8*(reg>>2) + 4*(lane>>5)  [m74/m101].
// ---------------------------------------------------------------------------
__global__ __launch_bounds__(256)
void attn_kernel(const bf16_t* __restrict__ qkv, const bf16_t* __restrict__ Vt,
                 bf16_t* __restrict__ attn_out) {
    int bh = blockIdx.x;        // linear%8 == bh%8 -> XCD pin
    int tile = blockIdx.y;      // y-major: tile 0 (32 iters) dispatches first
    int b = bh >> 4, h = bh & 15;

    int tid = threadIdx.x, wave = tid >> 6, lane = tid & 63;
    int l32 = lane & 31, hi = lane >> 5;
    int ih = wave & 1, jh = wave >> 1;

    const bf16_t* q_g = qkv + (size_t)b * SEQ * QKV_LD + (size_t)h * HD;
    const bf16_t* k_g = q_g + HID;
    const bf16_t* vt_g = Vt + (size_t)bh * HD * VT_LD;

    __shared__ __align__(16) bf16_t Ks[64][72];   // K tile [j][d]
    __shared__ __align__(16) bf16_t Vs[64][72];   // V^T tile [d][j]
    __shared__ __align__(16) bf16_t Ps[64][68];   // P [i][j], block-shared
    __shared__ float lsumS[4][32];                // per-wave row-sum partials

    const float QS = 0.125f * 1.44269504088896f;  // 1/sqrt(64) * log2(e)
    int i0 = tile * 64;

    // Q fragments (B-operand): Q[i = i0+ih*32+l32][k = ks*16 + hi*8 + e]
    bf16x8 qa[4];
    {
        const bf16_t* qrow = q_g + (size_t)(i0 + ih * 32 + l32) * QKV_LD + hi * 8;
#pragma unroll
        for (int ks = 0; ks < 4; ks++) {
            bf16x8 t = *(const bf16x8*)(qrow + ks * 16);
#pragma unroll
            for (int e = 0; e < 8; e++) qa[ks][e] = (bf16_t)((float)t[e] * QS);
        }
    }

    f32x16 o = {};
    float lsum = 0.0f;

    int sr = tid >> 2, sc = (tid & 3) * 8;  // staging: 64 rows x 2 b128/thread

    // preload first K/V tile into registers
    bf16x8 kr[2], vr[2];
#pragma unroll
    for (int t = 0; t < 2; t++) {
        kr[t] = *(const bf16x8*)(k_g + (size_t)(i0 + sr) * QKV_LD + sc + t * 32);
        vr[t] = *(const bf16x8*)(vt_g + (size_t)sr * VT_LD + i0 + sc + t * 32);
    }

    for (int j0 = i0; j0 < SEQ; j0 += 64) {
        __syncthreads();  // prev iteration's Ks/Vs/Ps readers done
#pragma unroll
        for (int t = 0; t < 2; t++) {
            *(bf16x8*)(&Ks[sr][sc + t * 32]) = kr[t];
            *(bf16x8*)(&Vs[sr][sc + t * 32]) = vr[t];
        }
        __syncthreads();

        // issue next tile's loads; land during compute
        if (j0 + 64 < SEQ) {
#pragma unroll
            for (int t = 0; t < 2; t++) {
                kr[t] = *(const bf16x8*)(k_g + (size_t)(j0 + 64 + sr) * QKV_LD + sc + t * 32);
                vr[t] = *(const bf16x8*)(vt_g + (size_t)sr * VT_LD + j0 + 64 + sc + t * 32);
            }
        }

        // --- QK: S^T quarter [32 j][32 i], 4 chained k-steps ---
        f32x16 st = {};
#pragma unroll
        for (int ks = 0; ks < 4; ks++) {
            bf16x8 ka = *(const bf16x8*)(&Ks[jh * 32 + l32][ks * 16 + hi * 8]);
            st = MFMA32(ka, qa[ks], st);
        }

        // --- P = exp2(st), mask (first iter only has the diagonal), pack ---
        if (j0 == i0) {
            int gi = i0 + ih * 32 + l32;
#pragma unroll
            for (int rq = 0; rq < 4; rq++) {
                bf16x4 pk;
#pragma unroll
                for (int r = 0; r < 4; r++) {
                    int gj = j0 + jh * 32 + 8 * rq + 4 * hi + r;
                    float p = (gj >= gi) ? __builtin_amdgcn_exp2f(st[rq * 4 + r]) : 0.0f;
                    lsum += p;
                    pk[r] = (bf16_t)p;
                }
                *(bf16x4*)(&Ps[ih * 32 + l32][jh * 32 + 8 * rq + 4 * hi]) = pk;
            }
        } else {
#pragma unroll
            for (int rq = 0; rq < 4; rq++) {
                bf16x4 pk;
#pragma unroll
                for (int r = 0; r < 4; r++) {
                    float p = __builtin_amdgcn_exp2f(st[rq * 4 + r]);
                    lsum += p;
                    pk[r] = (bf16_t)p;
                }
                *(bf16x4*)(&Ps[ih * 32 + l32][jh * 32 + 8 * rq + 4 * hi]) = pk;
            }
        }
        __syncthreads();  // Ps complete across waves

        // --- PV: O quarter [32 i][32 d] over 64 j (4 k-steps) ---
#pragma unroll
        for (int ks = 0; ks < 4; ks++) {
            bf16x8 pa = *(const bf16x8*)(&Ps[ih * 32 + l32][ks * 16 + hi * 8]);
            bf16x8 vb = *(const bf16x8*)(&Vs[jh * 32 + l32][ks * 16 + hi * 8]);
            o = MFMA32(pa, vb, o);
        }
    }

    // --- epilogue: combine row sums (lane pairs, then wave pairs via LDS) ---
    lsum += __shfl_xor(lsum, 32, 64);
    lsumS[wave][l32] = lsum;  // lanes l and l+32 write same value
    __syncthreads();

#pragma unroll
    for (int rq = 0; rq < 4; rq++) {
#pragma unroll
        for (int r = 0; r < 4; r++) {
            int il = 8 * rq + 4 * hi + r;                 // local i of this reg
            float rs = lsumS[ih][il] + lsumS[ih + 2][il]; // both j-halves
            int gi = i0 + ih * 32 + il;
            attn_out[(size_t)(b * SEQ + gi) * HID + h * HD + jh * 32 + l32] =
                (bf16_t)(o[rq * 4 + r] / rs);
        }
    }
}

// ---------------------------------------------------------------------------
extern "C" void kernel_launch(void* const* d_in, const int* in_sizes, int n_in,
                              void* d_out, int out_size, void* d_ws, size_t ws_size,
                              hipStream_t stream) {
    const float* x     = (const float*)d_in[0];
    const float* w_qkv = (const float*)d_in[1];
    const float* b_qkv = (const float*)d_in[2];
    const float* w_out = (const float*)d_in[3];
    const float* b_out = (const float*)d_in[4];
    float* out = (float*)d_out;

    char* ws = (char*)d_ws;
    bf16_t* xbf   = (bf16_t*)(ws);               // 8.39 MB; dead after QKV GEMM
    bf16_t* Vt    = (bf16_t*)(ws);               // 8.52 MB; overruns into wqkvT
                                                 // (dead by vt_transpose time)
    bf16_t* wqkvT = (bf16_t*)(ws + 8388608);     // 6.29 MB
    bf16_t* woutT = (bf16_t*)(ws + 14680064);    // 2.10 MB (never overwritten)
    bf16_t* qkv   = (bf16_t*)(ws + 16777216);    // 25.17 MB
    bf16_t* attn  = (bf16_t*)(ws + 41943040);    // 8.39 MB

    prep_kernel<<<8192, 256, 0, stream>>>(x, w_qkv, w_out, xbf, wqkvT, woutT);

    // 256^2 8-phase QKV GEMM: grid = (4096/256)*(3072/256) = 192 (%8==0)
    gemm_qkv_8ph<<<192, 512, 0, stream>>>(xbf, wqkvT, b_qkv, qkv,
                                          4096, 3072, 1024);

    vt_transpose<<<dim3(SEQ / 64, 2 * NHEAD), 256, 0, stream>>>(qkv, Vt);

    attn_kernel<<<dim3(2 * NHEAD, SEQ / 64), 256, 0, stream>>>(qkv, Vt, attn);

    gemm_bt_bias<float, 64><<<dim3(1024 / 64, 4096 / 128), 256, 0, stream>>>(
        attn, woutT, b_out, out, 4096, 1024, 1024);
}

// Round 2
// 172.788 us; speedup vs baseline: 1.0601x; 1.0511x over previous
//
#include <hip/hip_runtime.h>
#include <hip/hip_bf16.h>
#include <stdint.h>
#include <stddef.h>

typedef __bf16 bf16_t;
typedef __bf16 bf16x4 __attribute__((ext_vector_type(4)));
typedef __bf16 bf16x8 __attribute__((ext_vector_type(8)));
typedef float f32x4 __attribute__((ext_vector_type(4)));
typedef float f32x16 __attribute__((ext_vector_type(16)));

#define MFMA16(a, b, c) __builtin_amdgcn_mfma_f32_16x16x32_bf16(a, b, c, 0, 0, 0)
#define MFMA32(a, b, c) __builtin_amdgcn_mfma_f32_32x32x16_bf16(a, b, c, 0, 0, 0)

// async global->LDS, 16 B per lane; LDS dest = uniform base + lane*16
#define GLL16(g, l)                                                      \
    __builtin_amdgcn_global_load_lds(                                    \
        (const __attribute__((address_space(1))) void*)(g),              \
        (__attribute__((address_space(3))) void*)(l), 16, 0, 0)

#define SEQ 2048
#define NHEAD 16
#define HD 64
#define HID 1024
#define QKV_LD 3072
#define VT_LD 2080  // 2048 + 32 pad: breaks 4 KB power-of-2 L2 set aliasing

// ---------------------------------------------------------------------------
// Fused prep: cast x -> bf16 (blocks 0..4095), transpose+cast w_qkv
// (4096..7167), transpose+cast w_out (7168..8191).
// ---------------------------------------------------------------------------
__global__ __launch_bounds__(256)
void prep_kernel(const float* __restrict__ x, const float* __restrict__ w_qkv,
                 const float* __restrict__ w_out, bf16_t* __restrict__ xbf,
                 bf16_t* __restrict__ wqkvT, bf16_t* __restrict__ woutT) {
    int L = blockIdx.x;
    int tid = threadIdx.x;
    if (L < 4096) {  // cast x
        int i = (L * 256 + tid) * 4;
        float4 v = *(const float4*)(x + i);
        bf16x4 o = {(bf16_t)v.x, (bf16_t)v.y, (bf16_t)v.z, (bf16_t)v.w};
        *(bf16x4*)(xbf + i) = o;
        return;
    }
    __shared__ bf16_t tile[32][33];
    const float* W;
    bf16_t* Wt;
    int N, bx, by;
    if (L < 7168) {
        int r = L - 4096;
        W = w_qkv; Wt = wqkvT; N = 3072; bx = r % 96; by = r / 96;
    } else {
        int r = L - 7168;
        W = w_out; Wt = woutT; N = 1024; bx = r % 32; by = r / 32;
    }
    int K = 1024;
    int n0 = bx * 32, k0 = by * 32;
    int tx = tid & 31, ty = tid >> 5;  // 32 x 8
#pragma unroll
    for (int i = 0; i < 4; i++)
        tile[ty + i * 8][tx] = (bf16_t)W[(size_t)(k0 + ty + i * 8) * N + n0 + tx];
    __syncthreads();
#pragma unroll
    for (int i = 0; i < 4; i++)
        Wt[(size_t)(n0 + ty + i * 8) * K + k0 + tx] = tile[tx][ty + i * 8];
}

// ---------------------------------------------------------------------------
// QKV GEMM, 256x256 tile, BK=64, 8-phase schedule (T1+T2+T3+T4+T5).
// C[M][N] = A[M][K] @ Bt[N][K]^T + bias[N], bf16 out.
//
// NEW: V-tile workgroups (n0 >= 2048) skip the qkv store and instead write
// the transposed Vt[bh][d][s] directly from the accumulator (bf16x4 along s:
// quad gives 4 consecutive s -> 32-B runs per wave-store; adjacent mi stores
// complete the 64-B lines).  Values bit-identical to the old vt_transpose
// path (same acc+bias, same bf16 cast).  Kills the vt kernel + 8.4 MB qkv-V
// write + 8.4 MB re-read.
//
// 512 thr = 8 waves (2M x 4N); per-wave output 128x64; 16 MFMA_16x16x32 per
// phase.  LDS 128 KiB: [2 dbuf][256][64] A and B.  LDS chunk swizzle (T2):
// stored chunk c holds global chunk c ^ (row&7); GLL16 dest linear, global
// source pre-swizzled, same XOR on ds_read_b128.
//
// Staging: ph1 (t+1)B-h1 -> other buf; ph2 (t+1)A-h1 -> other buf;
// ph3 (t+2)B-h0 -> current buf (B fully read after ph2); ph4 (t+2)A-h0 ->
// current buf (A fully read after ph3).  Single vmcnt(4) drain per K-tile.
// ---------------------------------------------------------------------------
#define STAGE8(GB, LB, KOFF)                                                   \
    do {                                                                       \
        GLL16((GB) + (size_t)srow * K + (KOFF) + ssw,                          \
              (LB) + srow * 64 + (scl << 3));                                  \
        GLL16((GB) + (size_t)(srow + 64) * K + (KOFF) + ssw,                   \
              (LB) + (srow + 64) * 64 + (scl << 3));                           \
    } while (0)

__global__ __launch_bounds__(512, 2)
void gemm_qkv_8ph(const bf16_t* __restrict__ A, const bf16_t* __restrict__ Bt,
                  const float* __restrict__ bias, bf16_t* __restrict__ C,
                  bf16_t* __restrict__ Vt, int M, int N, int K) {
    __shared__ __align__(16) bf16_t As[2][256][64];
    __shared__ __align__(16) bf16_t Bs[2][256][64];

    // T1: bijective XCD swizzle (gridDim.x % 8 == 0)
    int nbx = N >> 8;
    int bid = blockIdx.x;
    int swz = (bid & 7) * (gridDim.x >> 3) + (bid >> 3);
    int m0 = (swz / nbx) << 8;
    int n0 = (swz % nbx) << 8;

    int tid = threadIdx.x;
    int lane = tid & 63;
    int wave = tid >> 6;
    int l16 = lane & 15, quad = lane >> 4;
    int wm = (wave >> 2) << 7;  // 0 / 128
    int wn = (wave & 3) << 6;   // 0 / 64 / 128 / 192

    // staging coords: 512 thr x 16 B = one 64-row sweep; 8 chunks/row
    int srow = tid >> 3;  // 0..63
    int scl = tid & 7;
    int ssw = ((scl ^ (srow & 7)) << 3);  // pre-swizzled global chunk offset

    const bf16_t* Ab = A + (size_t)m0 * K;
    const bf16_t* Bb = Bt + (size_t)n0 * K;

    f32x4 acc[8][4] = {};  // [msub*4+mt][nsub*2+nt]
    bf16x8 af[4][2], b0[2][2], b1[2][2];

    const int NT = K >> 6;  // 16 K-tiles of 64

    // ---- prologue: tile0 H1..H4, tile1 H1,H2; drain tile0 (vmcnt(4)) ----
    STAGE8(Bb, &Bs[0][0][0], 0);                        // t0 B-half0
    STAGE8(Ab, &As[0][0][0], 0);                        // t0 A-half0
    STAGE8(Bb + (size_t)128 * K, &Bs[0][128][0], 0);    // t0 B-half1
    STAGE8(Ab + (size_t)128 * K, &As[0][128][0], 0);    // t0 A-half1
    STAGE8(Bb, &Bs[1][0][0], 64);                       // t1 B-half0
    STAGE8(Ab, &As[1][0][0], 64);                       // t1 A-half0
    asm volatile("s_waitcnt vmcnt(4)" ::: "memory");
    __builtin_amdgcn_s_barrier();

    for (int t = 0; t < NT; t++) {
        int buf = t & 1;
        const bf16_t* Asb = &As[buf][0][0];
        const bf16_t* Bsb = &Bs[buf][0][0];
        int k1 = (t + 1) << 6;
        int k2 = (t + 2) << 6;

        // ===== phase 1: read A-msub0 + B-nsub0; stage (t+1) B-half1 =====
#pragma unroll
        for (int mt = 0; mt < 4; mt++) {
            int row = wm + mt * 16 + l16;
#pragma unroll
            for (int ks = 0; ks < 2; ks++)
                af[mt][ks] = *(const bf16x8*)(
                    Asb + row * 64 + (((ks * 4 + quad) ^ (row & 7)) << 3));
        }
#pragma unroll
        for (int nt = 0; nt < 2; nt++) {
            int row = wn + nt * 16 + l16;
#pragma unroll
            for (int ks = 0; ks < 2; ks++)
                b0[nt][ks] = *(const bf16x8*)(
                    Bsb + row * 64 + (((ks * 4 + quad) ^ (row & 7)) << 3));
        }
        if (t + 1 < NT) STAGE8(Bb + (size_t)128 * K, &Bs[buf ^ 1][128][0], k1);
        __builtin_amdgcn_s_barrier();
        asm volatile("s_waitcnt lgkmcnt(0)" ::: "memory");
        __builtin_amdgcn_s_setprio(1);
#pragma unroll
        for (int mt = 0; mt < 4; mt++)
#pragma unroll
            for (int nt = 0; nt < 2; nt++)
#pragma unroll
                for (int ks = 0; ks < 2; ks++)
                    acc[mt][nt] = MFMA16(af[mt][ks], b0[nt][ks], acc[mt][nt]);
        __builtin_amdgcn_s_setprio(0);
        __builtin_amdgcn_s_barrier();

        // ===== phase 2: read B-nsub1; stage (t+1) A-half1 =====
#pragma unroll
        for (int nt = 0; nt < 2; nt++) {
            int row = wn + 32 + nt * 16 + l16;
#pragma unroll
            for (int ks = 0; ks < 2; ks++)
                b1[nt][ks] = *(const bf16x8*)(
                    Bsb + row * 64 + (((ks * 4 + quad) ^ (row & 7)) << 3));
        }
        if (t + 1 < NT) STAGE8(Ab + (size_t)128 * K, &As[buf ^ 1][128][0], k1);
        __builtin_amdgcn_s_barrier();
        asm volatile("s_waitcnt lgkmcnt(0)" ::: "memory");
        __builtin_amdgcn_s_setprio(1);
#pragma unroll
        for (int mt = 0; mt < 4; mt++)
#pragma unroll
            for (int nt = 0; nt < 2; nt++)
#pragma unroll
                for (int ks = 0; ks < 2; ks++)
                    acc[mt][2 + nt] =
                        MFMA16(af[mt][ks], b1[nt][ks], acc[mt][2 + nt]);
        __builtin_amdgcn_s_setprio(0);
        __builtin_amdgcn_s_barrier();

        // ===== phase 3: read A-msub1; stage (t+2) B-half0 (current buf) =====
#pragma unroll
        for (int mt = 0; mt < 4; mt++) {
            int row = wm + 64 + mt * 16 + l16;
#pragma unroll
            for (int ks = 0; ks < 2; ks++)
                af[mt][ks] = *(const bf16x8*)(
                    Asb + row * 64 + (((ks * 4 + quad) ^ (row & 7)) << 3));
        }
        if (t + 2 < NT) STAGE8(Bb, &Bs[buf][0][0], k2);
        __builtin_amdgcn_s_barrier();
        asm volatile("s_waitcnt lgkmcnt(0)" ::: "memory");
        __builtin_amdgcn_s_setprio(1);
#pragma unroll
        for (int mt = 0; mt < 4; mt++)
#pragma unroll
            for (int nt = 0; nt < 2; nt++)
#pragma unroll
                for (int ks = 0; ks < 2; ks++)
                    acc[4 + mt][nt] =
                        MFMA16(af[mt][ks], b0[nt][ks], acc[4 + mt][nt]);
        __builtin_amdgcn_s_setprio(0);
        __builtin_amdgcn_s_barrier();

        // ===== phase 4: stage (t+2) A-half0 (current buf); counted drain ====
        if (t + 2 < NT) {
            STAGE8(Ab, &As[buf][0][0], k2);
            asm volatile("s_waitcnt vmcnt(4)" ::: "memory");
        } else if (t + 1 < NT) {
            asm volatile("s_waitcnt vmcnt(0)" ::: "memory");
        }
        __builtin_amdgcn_s_barrier();
        __builtin_amdgcn_s_setprio(1);
#pragma unroll
        for (int mt = 0; mt < 4; mt++)
#pragma unroll
            for (int nt = 0; nt < 2; nt++)
#pragma unroll
                for (int ks = 0; ks < 2; ks++)
                    acc[4 + mt][2 + nt] =
                        MFMA16(af[mt][ks], b1[nt][ks], acc[4 + mt][2 + nt]);
        __builtin_amdgcn_s_setprio(0);
        __builtin_amdgcn_s_barrier();
    }

    // ---- epilogue.  C/D: col=l16, row=quad*4+reg ----
    if (n0 < 2048) {
        // Q/K tiles: normal qkv store
#pragma unroll
        for (int mi = 0; mi < 8; mi++) {
            int row = m0 + wm + (mi >> 2) * 64 + (mi & 3) * 16 + quad * 4;
#pragma unroll
            for (int ni = 0; ni < 4; ni++) {
                int col = n0 + wn + (ni >> 1) * 32 + (ni & 1) * 16 + l16;
                float bv = bias[col];
#pragma unroll
                for (int r = 0; r < 4; r++)
                    C[(size_t)(row + r) * N + col] = (bf16_t)(acc[mi][ni][r] + bv);
            }
        }
    } else {
        // V tiles: transposed store into Vt[bh][d][s] (qkv V region unused)
#pragma unroll
        for (int mi = 0; mi < 8; mi++) {
            int row = m0 + wm + (mi >> 2) * 64 + (mi & 3) * 16 + quad * 4;
            int b = row >> 11, s = row & 2047;
#pragma unroll
            for (int ni = 0; ni < 4; ni++) {
                int col = n0 + wn + (ni >> 1) * 32 + (ni & 1) * 16 + l16;
                float bv = bias[col];
                int cv = col - 2048;
                int bh = b * 16 + (cv >> 6);
                bf16x4 pk;
#pragma unroll
                for (int r = 0; r < 4; r++)
                    pk[r] = (bf16_t)(acc[mi][ni][r] + bv);
                *(bf16x4*)(Vt + ((size_t)bh * HD + (cv & 63)) * VT_LD + s) = pk;
            }
        }
    }
}

// ---------------------------------------------------------------------------
// GEMM: C[M][N] = A[M][K] @ Bt[N][K]^T + bias[N].  bf16, fp32 accum, OutT out.
// 128xTN tile, BK=32, 256 thr, GLL width-16 staging into unpadded LDS.
// (out-projection: N=1024)
// ---------------------------------------------------------------------------
template <typename OutT, int TN>
__global__ __launch_bounds__(256)
void gemm_bt_bias(const bf16_t* __restrict__ A, const bf16_t* __restrict__ Bt,
                  const float* __restrict__ bias, OutT* __restrict__ C,
                  int M, int N, int K) {
    constexpr int NT = TN / 32;  // acc n-tiles per wave
    __shared__ __align__(16) bf16_t As[128][32];
    __shared__ __align__(16) bf16_t Bs[TN][32];

    int m0 = blockIdx.y * 128;
    int n0 = blockIdx.x * TN;
    int tid = threadIdx.x;
    int wave = tid >> 6, lane = tid & 63;
    int quad = lane >> 4, l16 = lane & 15;
    int wm = (wave >> 1) * 64, wn = (wave & 1) * (TN / 2);

    f32x4 acc[4][NT] = {};

    const bf16_t* a_base =
        A + (size_t)(m0 + wave * 32 + (lane >> 2)) * K + (lane & 3) * 8;
    const bf16_t* b_base =
        Bt + (size_t)(n0 + wave * (TN / 4) + (lane >> 2)) * K + (lane & 3) * 8;
    bf16_t* as_base = &As[wave * 32][0];
    bf16_t* bs_base = &Bs[wave * (TN / 4)][0];

    for (int k0 = 0; k0 < K; k0 += 32) {
        GLL16(a_base + k0, as_base);
        GLL16(a_base + 16 * K + k0, as_base + 16 * 32);
        GLL16(b_base + k0, bs_base);
        if (TN == 128) GLL16(b_base + 16 * K + k0, bs_base + 16 * 32);
        __syncthreads();

        bf16x8 af[4], bfr[NT];
#pragma unroll
        for (int t = 0; t < 4; t++)
            af[t] = *(const bf16x8*)(&As[wm + t * 16 + l16][quad * 8]);
#pragma unroll
        for (int t = 0; t < NT; t++)
            bfr[t] = *(const bf16x8*)(&Bs[wn + t * 16 + l16][quad * 8]);
#pragma unroll
        for (int mt = 0; mt < 4; mt++)
#pragma unroll
            for (int nt = 0; nt < NT; nt++)
                acc[mt][nt] = MFMA16(af[mt], bfr[nt], acc[mt][nt]);
        __syncthreads();
    }

#pragma unroll
    for (int mt = 0; mt < 4; mt++) {
        int row = m0 + wm + mt * 16 + quad * 4;
#pragma unroll
        for (int nt = 0; nt < NT; nt++) {
            int col = n0 + wn + nt * 16 + l16;
            float bv = bias[col];
#pragma unroll
            for (int r = 0; r < 4; r++)
                C[(size_t)(row + r) * N + col] = (OutT)(acc[mt][nt][r] + bv);
        }
    }
}

// ---------------------------------------------------------------------------
// Attention, mask j >= i, mfma_f32_32x32x16_bf16.
// TI=128 (NEW: was 64), BJ=64, 8 waves (ih=w>>1 in 0..3 = i 32-block,
// jh=w&1 = j/d half):
//   QK: S^T quarter = K[jh-half] . Q[ih-block]^T (A=K from LDS, B=Q regs).
//       C-layout: i = lane&31, j = r+8rq+4hi  [m74/m101].
//   PV: O quarter (ih, d-half jh) over all 64 j: A=Ps, B=Vs frags.
// One 64-row K/V tile now serves 128 q-rows: K/V stage traffic and barrier
// count per FLOP halve vs TI=64; chip K/V L2 reads 270->135 MB.
// Mask now covers first TWO j-blocks (j0 < i0+128), same per-element test.
// LDS 36.9 KB -> 2 blocks/CU (16 waves/CU, same occupancy as TI=64 config).
// Tile remap y<8?y:23-y pairs long+short tiles on co-resident wgs
// (pair cost const 34 iters vs worst-case 48).
// ---------------------------------------------------------------------------
__global__ __launch_bounds__(512, 4)
void attn_kernel(const bf16_t* __restrict__ qkv, const bf16_t* __restrict__ Vt,
                 bf16_t* __restrict__ attn_out) {
    int bh = blockIdx.x;        // linear%8 == bh%8 -> XCD pin
    int tile = (blockIdx.y < 8) ? blockIdx.y : (23 - blockIdx.y);
    int b = bh >> 4, h = bh & 15;

    int tid = threadIdx.x, wave = tid >> 6, lane = tid & 63;
    int l32 = lane & 31, hi = lane >> 5;
    int ih = wave >> 1, jh = wave & 1;

    const bf16_t* q_g = qkv + (size_t)b * SEQ * QKV_LD + (size_t)h * HD;
    const bf16_t* k_g = q_g + HID;
    const bf16_t* vt_g = Vt + (size_t)bh * HD * VT_LD;

    __shared__ __align__(16) bf16_t Ks[64][72];   // K tile [j][d]
    __shared__ __align__(16) bf16_t Vs[64][72];   // V^T tile [d][j]
    __shared__ __align__(16) bf16_t Ps[128][68];  // P [i][j], block-shared
    __shared__ float lsumS[8][32];                // per-wave row-sum partials

    const float QS = 0.125f * 1.44269504088896f;  // 1/sqrt(64) * log2(e)
    int i0 = tile * 128;

    // Q fragments (B-operand): Q[i = i0+ih*32+l32][k = ks*16 + hi*8 + e]
    bf16x8 qa[4];
    {
        const bf16_t* qrow = q_g + (size_t)(i0 + ih * 32 + l32) * QKV_LD + hi * 8;
#pragma unroll
        for (int ks = 0; ks < 4; ks++) {
            bf16x8 t = *(const bf16x8*)(qrow + ks * 16);
#pragma unroll
            for (int e = 0; e < 8; e++) qa[ks][e] = (bf16_t)((float)t[e] * QS);
        }
    }

    f32x16 o = {};
    float lsum = 0.0f;

    int sr = tid >> 3, sc = (tid & 7) * 8;  // staging: 64 rows, 1 b128/thread

    // preload first K/V tile into registers
    bf16x8 kr = *(const bf16x8*)(k_g + (size_t)(i0 + sr) * QKV_LD + sc);
    bf16x8 vr = *(const bf16x8*)(vt_g + (size_t)sr * VT_LD + i0 + sc);

    for (int j0 = i0; j0 < SEQ; j0 += 64) {
        __syncthreads();  // prev iteration's Ks/Vs/Ps readers done
        *(bf16x8*)(&Ks[sr][sc]) = kr;
        *(bf16x8*)(&Vs[sr][sc]) = vr;
        __syncthreads();

        // issue next tile's loads; land during compute
        if (j0 + 64 < SEQ) {
            kr = *(const bf16x8*)(k_g + (size_t)(j0 + 64 + sr) * QKV_LD + sc);
            vr = *(const bf16x8*)(vt_g + (size_t)sr * VT_LD + j0 + 64 + sc);
        }

        // --- QK: S^T quarter [32 j][32 i], 4 chained k-steps ---
        f32x16 st = {};
#pragma unroll
        for (int ks = 0; ks < 4; ks++) {
            bf16x8 ka = *(const bf16x8*)(&Ks[jh * 32 + l32][ks * 16 + hi * 8]);
            st = MFMA32(ka, qa[ks], st);
        }

        // --- P = exp2(st), mask (first two j-blocks carry the diagonal) ---
        if (j0 < i0 + 128) {
            int gi = i0 + ih * 32 + l32;
#pragma unroll
            for (int rq = 0; rq < 4; rq++) {
                bf16x4 pk;
#pragma unroll
                for (int r = 0; r < 4; r++) {
                    int gj = j0 + jh * 32 + 8 * rq + 4 * hi + r;
                    float p = (gj >= gi) ? __builtin_amdgcn_exp2f(st[rq * 4 + r]) : 0.0f;
                    lsum += p;
                    pk[r] = (bf16_t)p;
                }
                *(bf16x4*)(&Ps[ih * 32 + l32][jh * 32 + 8 * rq + 4 * hi]) = pk;
            }
        } else {
#pragma unroll
            for (int rq = 0; rq < 4; rq++) {
                bf16x4 pk;
#pragma unroll
                for (int r = 0; r < 4; r++) {
                    float p = __builtin_amdgcn_exp2f(st[rq * 4 + r]);
                    lsum += p;
                    pk[r] = (bf16_t)p;
                }
                *(bf16x4*)(&Ps[ih * 32 + l32][jh * 32 + 8 * rq + 4 * hi]) = pk;
            }
        }
        __syncthreads();  // Ps complete across waves

        // --- PV: O quarter [32 i][32 d] over 64 j (4 k-steps) ---
#pragma unroll
        for (int ks = 0; ks < 4; ks++) {
            bf16x8 pa = *(const bf16x8*)(&Ps[ih * 32 + l32][ks * 16 + hi * 8]);
            bf16x8 vb = *(const bf16x8*)(&Vs[jh * 32 + l32][ks * 16 + hi * 8]);
            o = MFMA32(pa, vb, o);
        }
    }

    // --- epilogue: combine row sums (lane pairs, then jh pairs via LDS) ---
    lsum += __shfl_xor(lsum, 32, 64);
    lsumS[wave][l32] = lsum;  // lanes l and l+32 write same value
    __syncthreads();

#pragma unroll
    for (int rq = 0; rq < 4; rq++) {
#pragma unroll
        for (int r = 0; r < 4; r++) {
            int il = 8 * rq + 4 * hi + r;                 // local i of this reg
            float rs = lsumS[ih * 2][il] + lsumS[ih * 2 + 1][il];  // both jh
            int gi = i0 + ih * 32 + il;
            attn_out[(size_t)(b * SEQ + gi) * HID + h * HD + jh * 32 + l32] =
                (bf16_t)(o[rq * 4 + r] / rs);
        }
    }
}

// ---------------------------------------------------------------------------
extern "C" void kernel_launch(void* const* d_in, const int* in_sizes, int n_in,
                              void* d_out, int out_size, void* d_ws, size_t ws_size,
                              hipStream_t stream) {
    const float* x     = (const float*)d_in[0];
    const float* w_qkv = (const float*)d_in[1];
    const float* b_qkv = (const float*)d_in[2];
    const float* w_out = (const float*)d_in[3];
    const float* b_out = (const float*)d_in[4];
    float* out = (float*)d_out;

    char* ws = (char*)d_ws;
    bf16_t* xbf   = (bf16_t*)(ws);               // 8.39 MB; dead after QKV GEMM
    bf16_t* wqkvT = (bf16_t*)(ws + 8388608);     // 6.29 MB
    bf16_t* woutT = (bf16_t*)(ws + 14680064);    // 2.10 MB
    bf16_t* qkv   = (bf16_t*)(ws + 16777216);    // 25.17 MB (V third unused)
    bf16_t* attn  = (bf16_t*)(ws + 41943040);    // 8.39 MB
    bf16_t* Vt    = (bf16_t*)(ws + 50331648);    // 8.52 MB; written by QKV GEMM

    prep_kernel<<<8192, 256, 0, stream>>>(x, w_qkv, w_out, xbf, wqkvT, woutT);

    // 256^2 8-phase QKV GEMM (V tiles fused-transposed into Vt): grid 192
    gemm_qkv_8ph<<<192, 512, 0, stream>>>(xbf, wqkvT, b_qkv, qkv, Vt,
                                          4096, 3072, 1024);

    attn_kernel<<<dim3(2 * NHEAD, SEQ / 128), 512, 0, stream>>>(qkv, Vt, attn);

    gemm_bt_bias<float, 64><<<dim3(1024 / 64, 4096 / 128), 256, 0, stream>>>(
        attn, woutT, b_out, out, 4096, 1024, 1024);
}